// Round 2
// baseline (685.047 us; speedup 1.0000x reference)
//
#include <hip/hip_runtime.h>

#define NTOK  384
#define SPANS 73920          // 384*385/2
#define MPAD  74752          // 292*256 (also 584*128)
#define HD    1024
#define BK    32
#define KTS   (HD / BK)      // 32 (small 128^2 kernel)
#define BK64  64
#define KT64  (HD / BK64)    // 16 (big 256^2 kernel)
#define GRID256 1168         // (MPAD/256) * (1024/256) = 292*4, divisible by 8
#define CPX256  (GRID256 / 8)

typedef unsigned short u16;
typedef __attribute__((ext_vector_type(8))) short short8;
typedef __attribute__((ext_vector_type(4))) float floatx4;

// gfx9 s_waitcnt immediate: vmcnt[3:0]|[15:14], expcnt[6:4], lgkmcnt[11:8]
#define VMCNT_IMM(N) (((N) & 0xF) | (((N) >> 4) << 14) | (0x7 << 4) | (0xF << 8))

__device__ __forceinline__ u16 f2bu(float x) {
  union { float f; unsigned u; } un; un.f = x;
  unsigned r = un.u + 0x7fffu + ((un.u >> 16) & 1u);   // RNE
  return (u16)(r >> 16);
}

__device__ __forceinline__ void gld_lds16(const void* g, void* l) {
  __builtin_amdgcn_global_load_lds(
      (const __attribute__((address_space(1))) void*)g,
      (__attribute__((address_space(3))) void*)l, 16, 0, 0);
}

// ---- prep: gather token embeddings as bf16 [384][1024] (A of the Y-GEMM) ----
__global__ void emb_gather(const int* __restrict__ sent, const int* __restrict__ pos,
                           const float* __restrict__ Wwrd, const float* __restrict__ Wpos,
                           u16* __restrict__ embB) {
  int t = blockIdx.x;           // token
  int c = threadIdx.x;          // 0..255
  int pt = pos[t], st = sent[t];
  #pragma unroll
  for (int u = 0; u < 4; ++u) {
    int col = u * 256 + c;
    float v = (col < 512) ? Wpos[(size_t)pt * 512 + col]
                          : Wwrd[(size_t)st * 512 + (col - 512)];
    embB[(size_t)t * HD + col] = f2bu(v);
  }
}

// ---- prep: span (i, end, 1/len) + scores init (folded) ----
__global__ void prep_spans(int* __restrict__ spI, int* __restrict__ spE, float* __restrict__ spInv,
                           float* __restrict__ scores, const float* __restrict__ bs2) {
  int rf = blockIdx.x * 256 + threadIdx.x;
  if (rf >= MPAD) return;
  int s = rf < SPANS ? rf : SPANS - 1;
  const int n = NTOK;
  double tn = 2.0 * n + 1.0;
  int i = (int)((tn - sqrt(tn * tn - 8.0 * (double)s)) * 0.5);
  if (i < 0) i = 0;
  if (i > n - 1) i = n - 1;
  #define OFF(ii) (((ii) * (2 * n - (ii) + 1)) / 2)
  while (i + 1 <= n - 1 && OFF(i + 1) <= s) ++i;
  while (i > 0 && OFF(i) > s) --i;
  int j = i + (s - OFF(i));
  #undef OFF
  spI[rf] = i;
  spE[rf] = j + 1;
  spInv[rf] = 1.0f / (float)(j + 1 - i);
  if (rf < SPANS) scores[rf] = bs2[0];
}

// ---- prep: transpose+cast the three 1024x1024 weight blocks to bf16 B^T [N][K] ----
__global__ void prep_castT(const float* __restrict__ Wd1, const float* __restrict__ Wd2,
                           const float* __restrict__ Ws1,
                           u16* __restrict__ o1, u16* __restrict__ o2, u16* __restrict__ o3) {
  int b = blockIdx.x;           // 3*1024 blocks
  int w = b >> 10, rem = b & 1023;
  int tk = rem >> 5, tn = rem & 31;
  const float* src = (w == 0) ? Wd1 : ((w == 1) ? Wd2 : Ws1);
  u16* dst = (w == 0) ? o1 : ((w == 1) ? o2 : o3);
  __shared__ u16 tile[32][33];
  int x = threadIdx.x & 31, y = threadIdx.x >> 5;   // y in 0..7
  int k0 = tk * 32, n0 = tn * 32;
  for (int yy = 0; yy < 32; yy += 8)
    tile[y + yy][x] = f2bu(src[(size_t)(k0 + y + yy) * HD + n0 + x]);
  __syncthreads();
  for (int yy = 0; yy < 32; yy += 8)
    dst[(size_t)(n0 + y + yy) * HD + k0 + x] = tile[x][y + yy];
}

// ---- prep: S0/S1/S2 = column sums of W_s1's feat rows (len/start/end, 16 each), exact fp32 ----
__global__ void prep_svec(const float* __restrict__ Ws1,
                          float* __restrict__ S0, float* __restrict__ S1v, float* __restrict__ S2v) {
  int c = blockIdx.x * 256 + threadIdx.x;
  if (c >= HD) return;
  float a = 0.f, b = 0.f, d = 0.f;
  for (int r = 0; r < 16; ++r) {
    a += Ws1[(size_t)(1024 + r) * HD + c];
    b += Ws1[(size_t)(1040 + r) * HD + c];
    d += Ws1[(size_t)(1056 + r) * HD + c];
  }
  S0[c] = a; S1v[c] = b; S2v[c] = d;
}

// ---- Qp = [0; cumsum(Y, rows)] fp32, per-column parallel scan ----
__global__ void yscan(const float* __restrict__ Y, float* __restrict__ Qp) {
  __shared__ float buf[NTOK];
  int c = blockIdx.x;           // 0..1023
  int t = threadIdx.x;          // 0..383
  buf[t] = Y[(size_t)t * HD + c];
  __syncthreads();
  #pragma unroll
  for (int off = 1; off < NTOK; off <<= 1) {
    float add = (t >= off) ? buf[t - off] : 0.f;
    __syncthreads();
    buf[t] += add;
    __syncthreads();
  }
  if (t == 0) Qp[c] = 0.f;
  Qp[(size_t)(t + 1) * HD + c] = buf[t];
}

// ---- expand: h1[s] = relu((Qp[e]-Qp[i])*inv + b1) -> bf16 [MPAD][1024] ----
__global__ void expand(const float* __restrict__ Qp, const int* __restrict__ spI,
                       const int* __restrict__ spE, const float* __restrict__ spInv,
                       const float* __restrict__ b1, u16* __restrict__ out) {
  int gid = blockIdx.x * 256 + threadIdx.x;   // MPAD*128 threads
  int row = gid >> 7;
  int c0 = (gid & 127) << 3;
  int i = spI[row], e = spE[row];
  float inv = spInv[row];
  const float* pe = Qp + (size_t)e * HD + c0;
  const float* pi = Qp + (size_t)i * HD + c0;
  const float* bb = b1 + c0;
  u16 tmp[8];
  #pragma unroll
  for (int u = 0; u < 8; ++u) {
    float v = (pe[u] - pi[u]) * inv + bb[u];
    v = v > 0.f ? v : 0.f;
    tmp[u] = f2bu(v);
  }
  *(uint4*)(out + (size_t)row * HD + c0) = *(const uint4*)tmp;
}

// ---- small GEMM kernel (kept only for the 384-row Y GEMM, EPI==2 path) ----
template <int EPI>
__global__ __launch_bounds__(256, 3) void gemm_bt(
    const u16* __restrict__ A, const u16* __restrict__ Bt,
    const float* __restrict__ bias, u16* __restrict__ C, float* __restrict__ Cf) {
  __shared__ u16 As[2][128 * BK];
  __shared__ u16 Bs[2][128 * BK];
  int bx = blockIdx.x;
  int nt = bx & 7, mt = bx >> 3;
  int m0 = mt * 128, n0 = nt * 128;
  int t = threadIdx.x, lane = t & 63, wid = t >> 6;
  int wm = wid >> 1, wn = wid & 1;
  int q = lane >> 4, r = lane & 15;

  floatx4 acc[4][4] = {};

  int dsub = (lane & 7) ^ ((lane >> 3) & 7);
  int row0 = wid * 16 + 2 * (lane >> 3) + (dsub >> 2);
  int voff = row0 * HD + (dsub & 3) * 8;
  const u16* gA0 = A  + (size_t)m0 * HD;
  const u16* gB0 = Bt + (size_t)n0 * HD;
  int ldsOff0 = wid * 512;
  int ldsOff1 = 2048 + wid * 512;

  auto stage = [&](int kt, int b) {
    const u16* pa = gA0 + voff + kt * BK;
    const u16* pb = gB0 + voff + kt * BK;
    gld_lds16(pa,                   &As[b][ldsOff0]);
    gld_lds16(pa + (size_t)64 * HD, &As[b][ldsOff1]);
    gld_lds16(pb,                   &Bs[b][ldsOff0]);
    gld_lds16(pb + (size_t)64 * HD, &Bs[b][ldsOff1]);
  };

  int oct = (((r & 1) << 2) + q) ^ ((r >> 1) & 7);
  int aoff[4], boff[4];
  #pragma unroll
  for (int x = 0; x < 4; ++x) {
    aoff[x] = (wm * 32 + x * 8 + (r >> 1)) * 64 + oct * 8;
    boff[x] = (wn * 32 + x * 8 + (r >> 1)) * 64 + oct * 8;
  }

  auto compute = [&](int b) {
    short8 af[4];
    #pragma unroll
    for (int x = 0; x < 4; ++x) af[x] = *(const short8*)(&As[b][aoff[x]]);
    #pragma unroll
    for (int ni = 0; ni < 4; ++ni) {
      short8 bf = *(const short8*)(&Bs[b][boff[ni]]);
      #pragma unroll
      for (int mi = 0; mi < 4; ++mi)
        acc[mi][ni] = __builtin_amdgcn_mfma_f32_16x16x32_bf16(af[mi], bf, acc[mi][ni], 0, 0, 0);
    }
  };

  stage(0, 0);
  #pragma unroll 1
  for (int kt = 0; kt < KTS; ++kt) {
    int cur = kt & 1;
    if (kt < KTS - 1) {
      stage(kt + 1, cur ^ 1);
      __builtin_amdgcn_s_waitcnt(VMCNT_IMM(4));
    } else {
      __builtin_amdgcn_s_waitcnt(VMCNT_IMM(0));
    }
    __builtin_amdgcn_s_barrier();
    compute(cur);
    __builtin_amdgcn_s_barrier();
  }

  // EPI==2: plain fp32 store
  #pragma unroll
  for (int mi = 0; mi < 4; ++mi) {
    int rowb = m0 + wm * 64 + mi * 16 + q * 4;
    #pragma unroll
    for (int ni = 0; ni < 4; ++ni) {
      int col = n0 + wn * 64 + ni * 16 + r;
      #pragma unroll
      for (int e = 0; e < 4; ++e)
        Cf[(size_t)(rowb + e) * HD + col] = acc[mi][ni][e];
    }
  }
}

// ---- big GEMM: faithful m201-style 256x256 / BK=64 / 8-wave / 4-phase-per-K-tile.
// LDS: 2 dbuf x (2 row-halves x 128 x 64) per matrix = 128 KiB total.
// Swizzle: 16B-chunk index XORed with (row&7), same involution on the pre-swizzled
// global source (gld_lds dest stays linear) and on the fragment ds_reads.
// Per phase p(0..3): read A-frags mi={2p,2p+1} (+ all B-frags at p==0), stage ONE
// half-tile (2 gld_lds), barrier, setprio(1), 16 MFMA, setprio(0), barrier.
// Half-tile order per K-tile j: [B-h0, B-h1, A-h0, A-h1]; prefetch offset +6 halves;
// counted vmcnt(4) only at p==3 (never 0 until the tail). Race-free:
//  - A-halves of K(kt+1) land in the opposite buffer,
//  - B-halves of K(kt+2) overwrite the current buffer's B only after phase 0
//    (the only phase that reads B) has fully completed (phase-0 end barrier).
template <int EPI>
__global__ __launch_bounds__(512, 2) void gemm256(
    const u16* __restrict__ A, const u16* __restrict__ Bt,
    const float* __restrict__ bias, u16* __restrict__ C,
    const int* __restrict__ spI, const int* __restrict__ spE,
    const float* __restrict__ S0, const float* __restrict__ S1v, const float* __restrict__ S2v,
    const float* __restrict__ Ws2, float* __restrict__ scores) {
  __shared__ u16 As[2][16384];   // [dbuf][half(8192) | row(64 u16) | chunk(8 u16)]
  __shared__ u16 Bs[2][16384];

  int swz = (blockIdx.x & 7) * CPX256 + (blockIdx.x >> 3);
  int mt = swz >> 2, nt = swz & 3;
  int m0 = mt * 256, n0 = nt * 256;
  int t = threadIdx.x, lane = t & 63, wid = t >> 6;   // 8 waves
  int wm = wid >> 2, wn = wid & 3;                    // 2 x 4 wave grid
  int q = lane >> 4, r = lane & 15;

  floatx4 acc[8][4] = {};

  // staging: one gld_lds op covers 64 rows (8 rows/wave); thread writes 16B at
  // stored-chunk (lane&7) of row (wid*8 + lane>>3); logical chunk = stored ^ (row&7).
  int clog = (lane & 7) ^ ((lane >> 3) & 7);
  int gvoff = (wid * 8 + (lane >> 3)) * HD + clog * 8;   // u16, kt-invariant
  const u16* gA0 = A  + (size_t)m0 * HD;
  const u16* gB0 = Bt + (size_t)n0 * HD;
  int lw = wid * 512;                                    // u16 dest within 64-row op

  auto stage_half = [&](int s) {
    int j = s >> 2, which = s & 3;      // which: 0=B-h0 1=B-h1 2=A-h0 3=A-h1
    int slot = j & 1;
    int rh = which & 1;
    const u16* g = ((which < 2) ? gB0 : gA0) + (size_t)(rh * 128) * HD + j * 64 + gvoff;
    u16* l = ((which < 2) ? Bs[slot] : As[slot]) + rh * 8192 + lw;
    gld_lds16(g, l);
    gld_lds16(g + (size_t)64 * HD, l + 4096);
  };

  // fragment read offsets (u16): lane(q,r) reads X[base+r][kh*32 + q*8 .. +7]
  // stored at chunk (q+4*kh)^(r&7) of row base+r.
  int aoff[8][2], boff[4][2];
  #pragma unroll
  for (int mi = 0; mi < 8; ++mi)
    #pragma unroll
    for (int kh = 0; kh < 2; ++kh)
      aoff[mi][kh] = wm * 8192 + (mi * 16 + r) * 64 + (((q + 4 * kh) ^ (r & 7)) * 8);
  #pragma unroll
  for (int ni = 0; ni < 4; ++ni)
    #pragma unroll
    for (int kh = 0; kh < 2; ++kh)
      boff[ni][kh] = (wn >> 1) * 8192 + ((wn & 1) * 64 + ni * 16 + r) * 64 +
                     (((q + 4 * kh) ^ (r & 7)) * 8);

  // prologue: K0 complete + K1 B-halves = 6 half-tiles; drain K0 (leave 4 loads)
  #pragma unroll
  for (int s = 0; s < 6; ++s) stage_half(s);
  __builtin_amdgcn_s_waitcnt(VMCNT_IMM(4));
  __builtin_amdgcn_s_barrier();

  #pragma unroll 1
  for (int kt = 0; kt < KT64; ++kt) {
    int slot = kt & 1;
    const u16* sA = As[slot];
    const u16* sB = Bs[slot];
    int sbase = 4 * kt + 6;
    short8 bf[4][2];

    #pragma unroll
    for (int p = 0; p < 4; ++p) {
      short8 af[2][2];
      #pragma unroll
      for (int d = 0; d < 2; ++d)
        #pragma unroll
        for (int kh = 0; kh < 2; ++kh)
          af[d][kh] = *(const short8*)(sA + aoff[2 * p + d][kh]);
      if (p == 0) {
        #pragma unroll
        for (int ni = 0; ni < 4; ++ni)
          #pragma unroll
          for (int kh = 0; kh < 2; ++kh)
            bf[ni][kh] = *(const short8*)(sB + boff[ni][kh]);
      }
      int s = sbase + p;
      if (s < 4 * KT64) stage_half(s);
      if (p == 3) {
        if (kt < KT64 - 2) __builtin_amdgcn_s_waitcnt(VMCNT_IMM(4));
        else               __builtin_amdgcn_s_waitcnt(VMCNT_IMM(0));
      }
      __builtin_amdgcn_s_barrier();
      __builtin_amdgcn_s_setprio(1);
      #pragma unroll
      for (int kh = 0; kh < 2; ++kh)
        #pragma unroll
        for (int ni = 0; ni < 4; ++ni)
          #pragma unroll
          for (int d = 0; d < 2; ++d)
            acc[2 * p + d][ni] = __builtin_amdgcn_mfma_f32_16x16x32_bf16(
                af[d][kh], bf[ni][kh], acc[2 * p + d][ni], 0, 0, 0);
      __builtin_amdgcn_s_setprio(0);
      __builtin_amdgcn_s_barrier();
    }
  }

  if (EPI == 0) {
    #pragma unroll
    for (int ni = 0; ni < 4; ++ni) {
      int col = n0 + wn * 64 + ni * 16 + r;
      float bcol = bias[col];
      #pragma unroll
      for (int mi = 0; mi < 8; ++mi) {
        int rowb = m0 + wm * 128 + mi * 16 + q * 4;
        #pragma unroll
        for (int e = 0; e < 4; ++e) {
          float v = acc[mi][ni][e] + bcol;
          v = v > 0.f ? v : 0.f;
          C[(size_t)(rowb + e) * HD + col] = f2bu(v);
        }
      }
    }
  } else {
    float bcol[4], s0c[4], s1c[4], s2c[4], wsc[4];
    #pragma unroll
    for (int ni = 0; ni < 4; ++ni) {
      int col = n0 + wn * 64 + ni * 16 + r;
      bcol[ni] = bias[col]; s0c[ni] = S0[col]; s1c[ni] = S1v[col];
      s2c[ni] = S2v[col];  wsc[ni] = Ws2[col];
    }
    #pragma unroll
    for (int mi = 0; mi < 8; ++mi) {
      int rowb = m0 + wm * 128 + mi * 16 + q * 4;
      #pragma unroll
      for (int e = 0; e < 4; ++e) {
        int row = rowb + e;
        float fi = (float)spI[row];
        float fe = (float)spE[row];
        float fl = fe - fi;
        float p = 0.f;
        #pragma unroll
        for (int ni = 0; ni < 4; ++ni) {
          float v = acc[mi][ni][e] + bcol[ni] + fl * s0c[ni] + fi * s1c[ni] + fe * s2c[ni];
          v = v > 0.f ? v : 0.f;
          p += v * wsc[ni];
        }
        p += __shfl_xor(p, 1);
        p += __shfl_xor(p, 2);
        p += __shfl_xor(p, 4);
        p += __shfl_xor(p, 8);
        if (r == 0 && row < SPANS) atomicAdd(&scores[row], p);
      }
    }
  }
}

extern "C" void kernel_launch(void* const* d_in, const int* in_sizes, int n_in,
                              void* d_out, int out_size, void* d_ws, size_t ws_size,
                              hipStream_t stream) {
  const int*   sent = (const int*)d_in[0];
  const int*   pos  = (const int*)d_in[1];
  const float* Wwrd = (const float*)d_in[2];
  const float* Wpos = (const float*)d_in[3];
  const float* Wd1  = (const float*)d_in[4];
  const float* bd1  = (const float*)d_in[5];
  const float* Wd2  = (const float*)d_in[6];
  const float* bd2  = (const float*)d_in[7];
  const float* Ws1  = (const float*)d_in[8];
  const float* bs1  = (const float*)d_in[9];
  const float* Ws2  = (const float*)d_in[10];
  const float* bs2  = (const float*)d_in[11];
  float* scores = (float*)d_out;

  char* w = (char*)d_ws;
  size_t o = 0;
  auto alloc = [&](size_t bytes) {
    char* p = w + o;
    o = (o + bytes + 255) & ~(size_t)255;
    return p;
  };
  int*   spI   = (int*)  alloc((size_t)MPAD * 4);
  int*   spE   = (int*)  alloc((size_t)MPAD * 4);
  float* spInv = (float*)alloc((size_t)MPAD * 4);
  float* S0    = (float*)alloc(4096);
  float* S1v   = (float*)alloc(4096);
  float* S2v   = (float*)alloc(4096);
  u16*   embB  = (u16*)  alloc((size_t)NTOK * HD * 2);
  float* Ybuf  = (float*)alloc((size_t)NTOK * HD * 4);
  float* Qp    = (float*)alloc((size_t)(NTOK + 1) * HD * 4);
  u16* Wd1t = (u16*)alloc((size_t)HD * HD * 2);
  u16* Wd2t = (u16*)alloc((size_t)HD * HD * 2);
  u16* Ws1t = (u16*)alloc((size_t)HD * HD * 2);
  u16* bufA = (u16*)alloc((size_t)MPAD * HD * 2);
  u16* bufB = (u16*)alloc((size_t)MPAD * HD * 2);

  emb_gather<<<NTOK, 256, 0, stream>>>(sent, pos, Wwrd, Wpos, embB);
  prep_spans<<<(MPAD + 255) / 256, 256, 0, stream>>>(spI, spE, spInv, scores, bs2);
  prep_castT<<<3 * 1024, 256, 0, stream>>>(Wd1, Wd2, Ws1, Wd1t, Wd2t, Ws1t);
  prep_svec <<<4, 256, 0, stream>>>(Ws1, S0, S1v, S2v);

  // Y = emb @ Wd1  (384x1024x1024, 24 blocks, fp32 out)
  gemm_bt<2><<<(NTOK / 128) * 8, 256, 0, stream>>>(embB, Wd1t, nullptr, nullptr, Ybuf);
  yscan<<<HD, NTOK, 0, stream>>>(Ybuf, Qp);
  expand<<<MPAD / 2, 256, 0, stream>>>(Qp, spI, spE, spInv, bd1, bufA);

  gemm256<0><<<GRID256, 512, 0, stream>>>(bufA, Wd2t, bd2, bufB,
                                          nullptr, nullptr, nullptr, nullptr, nullptr,
                                          nullptr, nullptr);
  gemm256<1><<<GRID256, 512, 0, stream>>>(bufB, Ws1t, bs1, nullptr,
                                          spI, spE, S0, S1v, S2v, Ws2, scores);
}

// Round 3
// 634.401 us; speedup vs baseline: 1.0798x; 1.0798x over previous
//
#include <hip/hip_runtime.h>

#define NTOK  384
#define SPANS 73920          // 384*385/2
#define MTILES 584           // 73*8 so grid=584*8 maps cleanly onto 8 XCDs
#define MPAD  (MTILES * 128) // 74752
#define HD    1024
#define BK    32
#define KTS   (HD / BK)      // 32

typedef unsigned short u16;
typedef __attribute__((ext_vector_type(8))) short short8;
typedef __attribute__((ext_vector_type(4))) float floatx4;

// gfx9 s_waitcnt immediate: vmcnt[3:0]|[15:14], expcnt[6:4], lgkmcnt[11:8]
#define VMCNT_IMM(N) (((N) & 0xF) | (((N) >> 4) << 14) | (0x7 << 4) | (0xF << 8))

__device__ __forceinline__ u16 f2bu(float x) {
  union { float f; unsigned u; } un; un.f = x;
  unsigned r = un.u + 0x7fffu + ((un.u >> 16) & 1u);   // RNE
  return (u16)(r >> 16);
}

__device__ __forceinline__ void gld_lds16(const void* g, void* l) {
  __builtin_amdgcn_global_load_lds(
      (const __attribute__((address_space(1))) void*)g,
      (__attribute__((address_space(3))) void*)l, 16, 0, 0);
}

// ---- prep: gather token embeddings as bf16 [384][1024] (A of the Y-GEMM) ----
__global__ void emb_gather(const int* __restrict__ sent, const int* __restrict__ pos,
                           const float* __restrict__ Wwrd, const float* __restrict__ Wpos,
                           u16* __restrict__ embB) {
  int t = blockIdx.x;           // token
  int c = threadIdx.x;          // 0..255
  int pt = pos[t], st = sent[t];
  #pragma unroll
  for (int u = 0; u < 4; ++u) {
    int col = u * 256 + c;
    float v = (col < 512) ? Wpos[(size_t)pt * 512 + col]
                          : Wwrd[(size_t)st * 512 + (col - 512)];
    embB[(size_t)t * HD + col] = f2bu(v);
  }
}

// ---- prep: span (i, end, 1/len) + scores init (folded) ----
__global__ void prep_spans(int* __restrict__ spI, int* __restrict__ spE, float* __restrict__ spInv,
                           float* __restrict__ scores, const float* __restrict__ bs2) {
  int rf = blockIdx.x * 256 + threadIdx.x;
  if (rf >= MPAD) return;
  int s = rf < SPANS ? rf : SPANS - 1;
  const int n = NTOK;
  double tn = 2.0 * n + 1.0;
  int i = (int)((tn - sqrt(tn * tn - 8.0 * (double)s)) * 0.5);
  if (i < 0) i = 0;
  if (i > n - 1) i = n - 1;
  #define OFF(ii) (((ii) * (2 * n - (ii) + 1)) / 2)
  while (i + 1 <= n - 1 && OFF(i + 1) <= s) ++i;
  while (i > 0 && OFF(i) > s) --i;
  int j = i + (s - OFF(i));
  #undef OFF
  spI[rf] = i;
  spE[rf] = j + 1;
  spInv[rf] = 1.0f / (float)(j + 1 - i);
  if (rf < SPANS) scores[rf] = bs2[0];
}

// ---- prep: transpose+cast the three 1024x1024 weight blocks to bf16 B^T [N][K] ----
__global__ void prep_castT(const float* __restrict__ Wd1, const float* __restrict__ Wd2,
                           const float* __restrict__ Ws1,
                           u16* __restrict__ o1, u16* __restrict__ o2, u16* __restrict__ o3) {
  int b = blockIdx.x;           // 3*1024 blocks
  int w = b >> 10, rem = b & 1023;
  int tk = rem >> 5, tn = rem & 31;
  const float* src = (w == 0) ? Wd1 : ((w == 1) ? Wd2 : Ws1);
  u16* dst = (w == 0) ? o1 : ((w == 1) ? o2 : o3);
  __shared__ u16 tile[32][33];
  int x = threadIdx.x & 31, y = threadIdx.x >> 5;   // y in 0..7
  int k0 = tk * 32, n0 = tn * 32;
  for (int yy = 0; yy < 32; yy += 8)
    tile[y + yy][x] = f2bu(src[(size_t)(k0 + y + yy) * HD + n0 + x]);
  __syncthreads();
  for (int yy = 0; yy < 32; yy += 8)
    dst[(size_t)(n0 + y + yy) * HD + k0 + x] = tile[x][y + yy];
}

// ---- prep: S0/S1/S2 = column sums of W_s1's feat rows (len/start/end, 16 each), exact fp32 ----
__global__ void prep_svec(const float* __restrict__ Ws1,
                          float* __restrict__ S0, float* __restrict__ S1v, float* __restrict__ S2v) {
  int c = blockIdx.x * 256 + threadIdx.x;
  if (c >= HD) return;
  float a = 0.f, b = 0.f, d = 0.f;
  for (int r = 0; r < 16; ++r) {
    a += Ws1[(size_t)(1024 + r) * HD + c];
    b += Ws1[(size_t)(1040 + r) * HD + c];
    d += Ws1[(size_t)(1056 + r) * HD + c];
  }
  S0[c] = a; S1v[c] = b; S2v[c] = d;
}

// ---- Qp = [0; cumsum(Y, rows)] fp32, per-column parallel scan ----
__global__ void yscan(const float* __restrict__ Y, float* __restrict__ Qp) {
  __shared__ float buf[NTOK];
  int c = blockIdx.x;           // 0..1023
  int t = threadIdx.x;          // 0..383
  buf[t] = Y[(size_t)t * HD + c];
  __syncthreads();
  #pragma unroll
  for (int off = 1; off < NTOK; off <<= 1) {
    float add = (t >= off) ? buf[t - off] : 0.f;
    __syncthreads();
    buf[t] += add;
    __syncthreads();
  }
  if (t == 0) Qp[c] = 0.f;
  Qp[(size_t)(t + 1) * HD + c] = buf[t];
}

// ---- expand: h1[s] = relu((Qp[e]-Qp[i])*inv + b1) -> bf16 [MPAD][1024] ----
// Replaces the 1.6e11-FLOP GEMM1: matmul is linear in the span mean, so
// mean@W1 = (prefix(Y)[e]-prefix(Y)[i])*inv with Y = emb@W1 (tiny GEMM).
__global__ void expand(const float* __restrict__ Qp, const int* __restrict__ spI,
                       const int* __restrict__ spE, const float* __restrict__ spInv,
                       const float* __restrict__ b1, u16* __restrict__ out) {
  int gid = blockIdx.x * 256 + threadIdx.x;   // MPAD*128 threads
  int row = gid >> 7;
  int c0 = (gid & 127) << 3;
  int i = spI[row], e = spE[row];
  float inv = spInv[row];
  const float* pe = Qp + (size_t)e * HD + c0;
  const float* pi = Qp + (size_t)i * HD + c0;
  const float* bb = b1 + c0;
  u16 tmp[8];
  #pragma unroll
  for (int u = 0; u < 8; ++u) {
    float v = (pe[u] - pi[u]) * inv + bb[u];
    v = v > 0.f ? v : 0.f;
    tmp[u] = f2bu(v);
  }
  *(uint4*)(out + (size_t)row * HD + c0) = *(const uint4*)tmp;
}

// ---- GEMM: C[M,1024] = A[M,1024] @ B^T[1024,1024]^T (+ bias, relu)
// R7 structure: 128x128 tile, 4 waves of 64x64, 16x16x32 MFMA, BK=32,
// 0-conflict stripe layout (2 rows per 128-B stripe), ping-pong + vmcnt(4).
// Round-3 change: __launch_bounds__(256, 5) -> 5 blocks/CU (LDS 32 KiB/block,
// 160 KiB total; VGPR cap 102 >= 56 so no spill). Mechanism: each block's
// vmcnt+barrier drain is covered by 4 other resident blocks (m114 overlap).
// EPI==0: relu+bias, store bf16 C.
// EPI==1: + feats affine, relu, dot W_s2, atomicAdd scores.
// EPI==2: plain fp32 store (no bias/relu), simple block mapping (small Y-GEMM).
template <int EPI>
__global__ __launch_bounds__(256, 5) void gemm_bt(
    const u16* __restrict__ A, const u16* __restrict__ Bt,
    const float* __restrict__ bias, u16* __restrict__ C, float* __restrict__ Cf,
    const int* __restrict__ spI, const int* __restrict__ spE,
    const float* __restrict__ S0, const float* __restrict__ S1v, const float* __restrict__ S2v,
    const float* __restrict__ Ws2, float* __restrict__ scores) {
  __shared__ u16 As[2][128 * BK];   // 8 KB per buffer; [stripe(64)][128B]
  __shared__ u16 Bs[2][128 * BK];
  int bx = blockIdx.x;
  int mt, nt;
  if (EPI == 2) {
    nt = bx & 7; mt = bx >> 3;      // tiny GEMM: plain mapping
  } else {
    int xcd = bx & 7, k = bx >> 3;
    nt = k & 7;
    mt = xcd + 8 * (k >> 3);        // mt%8 == xcd; blocks per XCD share mt (A L2 reuse)
  }
  int m0 = mt * 128, n0 = nt * 128;
  int t = threadIdx.x, lane = t & 63, wid = t >> 6;
  int wm = wid >> 1, wn = wid & 1;
  int q = lane >> 4, r = lane & 15;

  floatx4 acc[4][4] = {};

  // ---- staging geometry (stripe s holds rows 2s,2s+1; sub=(row&1)*4+koct at
  // octet sub^(s&7); one DMA op = 16 rows x 64B, swizzle invariant under +64 rows) ----
  int dsub = (lane & 7) ^ ((lane >> 3) & 7);
  int row0 = wid * 16 + 2 * (lane >> 3) + (dsub >> 2);
  int voff = row0 * HD + (dsub & 3) * 8;          // u16 elems; kt-invariant
  const u16* gA0 = A  + (size_t)m0 * HD;
  const u16* gB0 = Bt + (size_t)n0 * HD;
  int ldsOff0 = wid * 512;                        // u16; wave-uniform dests
  int ldsOff1 = 2048 + wid * 512;                 // +64 rows = +32 stripes

  auto stage = [&](int kt, int b) {
    const u16* pa = gA0 + voff + kt * BK;
    const u16* pb = gB0 + voff + kt * BK;
    gld_lds16(pa,                   &As[b][ldsOff0]);
    gld_lds16(pa + (size_t)64 * HD, &As[b][ldsOff1]);
    gld_lds16(pb,                   &Bs[b][ldsOff0]);
    gld_lds16(pb + (size_t)64 * HD, &Bs[b][ldsOff1]);
  };

  // ---- fragment read offsets (u16 elements) ----
  int oct = (((r & 1) << 2) + q) ^ ((r >> 1) & 7);
  int aoff[4], boff[4];
  #pragma unroll
  for (int x = 0; x < 4; ++x) {
    aoff[x] = (wm * 32 + x * 8 + (r >> 1)) * 64 + oct * 8;
    boff[x] = (wn * 32 + x * 8 + (r >> 1)) * 64 + oct * 8;
  }

  auto compute = [&](int b) {
    short8 af[4];
    #pragma unroll
    for (int x = 0; x < 4; ++x) af[x] = *(const short8*)(&As[b][aoff[x]]);
    #pragma unroll
    for (int ni = 0; ni < 4; ++ni) {
      short8 bf = *(const short8*)(&Bs[b][boff[ni]]);
      #pragma unroll
      for (int mi = 0; mi < 4; ++mi)
        acc[mi][ni] = __builtin_amdgcn_mfma_f32_16x16x32_bf16(af[mi], bf, acc[mi][ni], 0, 0, 0);
    }
  };

  stage(0, 0);
  #pragma unroll 1
  for (int kt = 0; kt < KTS; ++kt) {
    int cur = kt & 1;
    if (kt < KTS - 1) {
      stage(kt + 1, cur ^ 1);
      __builtin_amdgcn_s_waitcnt(VMCNT_IMM(4));   // kt's 4 stage ops done; kt+1's in flight
    } else {
      __builtin_amdgcn_s_waitcnt(VMCNT_IMM(0));
    }
    __builtin_amdgcn_s_barrier();
    compute(cur);
    __builtin_amdgcn_s_barrier();                 // all waves done reading buf cur
  }

  if (EPI == 2) {
    #pragma unroll
    for (int mi = 0; mi < 4; ++mi) {
      int rowb = m0 + wm * 64 + mi * 16 + q * 4;
      #pragma unroll
      for (int ni = 0; ni < 4; ++ni) {
        int col = n0 + wn * 64 + ni * 16 + r;
        #pragma unroll
        for (int e = 0; e < 4; ++e)
          Cf[(size_t)(rowb + e) * HD + col] = acc[mi][ni][e];
      }
    }
  } else if (EPI == 0) {
    #pragma unroll
    for (int mi = 0; mi < 4; ++mi) {
      int rowb = m0 + wm * 64 + mi * 16 + q * 4;
      #pragma unroll
      for (int ni = 0; ni < 4; ++ni) {
        int col = n0 + wn * 64 + ni * 16 + r;
        float bcol = bias[col];
        #pragma unroll
        for (int e = 0; e < 4; ++e) {
          float v = acc[mi][ni][e] + bcol;
          v = v > 0.f ? v : 0.f;
          C[(size_t)(rowb + e) * HD + col] = f2bu(v);
        }
      }
    }
  } else {
    float bcol[4], s0c[4], s1c[4], s2c[4], wsc[4];
    #pragma unroll
    for (int ni = 0; ni < 4; ++ni) {
      int col = n0 + wn * 64 + ni * 16 + r;
      bcol[ni] = bias[col]; s0c[ni] = S0[col]; s1c[ni] = S1v[col];
      s2c[ni] = S2v[col];  wsc[ni] = Ws2[col];
    }
    #pragma unroll
    for (int mi = 0; mi < 4; ++mi) {
      int rowb = m0 + wm * 64 + mi * 16 + q * 4;
      #pragma unroll
      for (int e = 0; e < 4; ++e) {
        int row = rowb + e;
        float fi = (float)spI[row];
        float fe = (float)spE[row];
        float fl = fe - fi;
        float p = 0.f;
        #pragma unroll
        for (int ni = 0; ni < 4; ++ni) {
          float v = acc[mi][ni][e] + bcol[ni] + fl * s0c[ni] + fi * s1c[ni] + fe * s2c[ni];
          v = v > 0.f ? v : 0.f;
          p += v * wsc[ni];
        }
        p += __shfl_xor(p, 1);
        p += __shfl_xor(p, 2);
        p += __shfl_xor(p, 4);
        p += __shfl_xor(p, 8);
        if (r == 0 && row < SPANS) atomicAdd(&scores[row], p);
      }
    }
  }
}

extern "C" void kernel_launch(void* const* d_in, const int* in_sizes, int n_in,
                              void* d_out, int out_size, void* d_ws, size_t ws_size,
                              hipStream_t stream) {
  const int*   sent = (const int*)d_in[0];
  const int*   pos  = (const int*)d_in[1];
  const float* Wwrd = (const float*)d_in[2];
  const float* Wpos = (const float*)d_in[3];
  const float* Wd1  = (const float*)d_in[4];
  const float* bd1  = (const float*)d_in[5];
  const float* Wd2  = (const float*)d_in[6];
  const float* bd2  = (const float*)d_in[7];
  const float* Ws1  = (const float*)d_in[8];
  const float* bs1  = (const float*)d_in[9];
  const float* Ws2  = (const float*)d_in[10];
  const float* bs2  = (const float*)d_in[11];
  float* scores = (float*)d_out;

  char* w = (char*)d_ws;
  size_t o = 0;
  auto alloc = [&](size_t bytes) {
    char* p = w + o;
    o = (o + bytes + 255) & ~(size_t)255;
    return p;
  };
  int*   spI   = (int*)  alloc((size_t)MPAD * 4);
  int*   spE   = (int*)  alloc((size_t)MPAD * 4);
  float* spInv = (float*)alloc((size_t)MPAD * 4);
  float* S0    = (float*)alloc(4096);
  float* S1v   = (float*)alloc(4096);
  float* S2v   = (float*)alloc(4096);
  u16*   embB  = (u16*)  alloc((size_t)NTOK * HD * 2);
  float* Ybuf  = (float*)alloc((size_t)NTOK * HD * 4);
  float* Qp    = (float*)alloc((size_t)(NTOK + 1) * HD * 4);
  u16* Wd1t = (u16*)alloc((size_t)HD * HD * 2);
  u16* Wd2t = (u16*)alloc((size_t)HD * HD * 2);
  u16* Ws1t = (u16*)alloc((size_t)HD * HD * 2);
  u16* bufA = (u16*)alloc((size_t)MPAD * HD * 2);
  u16* bufB = (u16*)alloc((size_t)MPAD * HD * 2);

  emb_gather<<<NTOK, 256, 0, stream>>>(sent, pos, Wwrd, Wpos, embB);
  prep_spans<<<(MPAD + 255) / 256, 256, 0, stream>>>(spI, spE, spInv, scores, bs2);
  prep_castT<<<3 * 1024, 256, 0, stream>>>(Wd1, Wd2, Ws1, Wd1t, Wd2t, Ws1t);
  prep_svec <<<4, 256, 0, stream>>>(Ws1, S0, S1v, S2v);

  // Y = emb @ Wd1  (384x1024x1024, 24 blocks, fp32 out)
  gemm_bt<2><<<(NTOK / 128) * 8, 256, 0, stream>>>(embB, Wd1t, nullptr, nullptr, Ybuf,
                                                   nullptr, nullptr, nullptr, nullptr, nullptr,
                                                   nullptr, nullptr);
  yscan<<<HD, NTOK, 0, stream>>>(Ybuf, Qp);
  expand<<<MPAD / 2, 256, 0, stream>>>(Qp, spI, spE, spInv, bd1, bufA);

  gemm_bt<0><<<MTILES * 8, 256, 0, stream>>>(bufA, Wd2t, bd2, bufB, nullptr,
                                             nullptr, nullptr, nullptr, nullptr, nullptr,
                                             nullptr, nullptr);
  gemm_bt<1><<<MTILES * 8, 256, 0, stream>>>(bufB, Ws1t, bs1, nullptr, nullptr,
                                             spI, spE, S0, S1v, S2v, Ws2, scores);
}